// Round 5
// baseline (827.439 us; speedup 1.0000x reference)
//
#include <hip/hip_runtime.h>
#include <hip/hip_bf16.h>
#include <stdint.h>

#define N_NODES 50000
#define N_EDGES 500000
#define DIM 512

typedef unsigned short u16;
typedef unsigned int u32;
typedef __bf16 bf16x8 __attribute__((ext_vector_type(8)));
typedef float f32x4 __attribute__((ext_vector_type(4)));

static __device__ __forceinline__ u16 f2bf(float f) {
  union { __bf16 b; u16 u; } cv; cv.b = (__bf16)f; return cv.u;
}
static __device__ __forceinline__ float bf2f(u16 u) {
  union { u16 u; __bf16 b; } cv; cv.u = u; return (float)cv.b;
}

// ---------------- deg zero (rocclr blit path avoided) ----------------
__global__ void k_zero(int4* __restrict__ deg4) {
  int t = blockIdx.x * 256 + threadIdx.x;
  if (t < 12500) deg4[t] = make_int4(0, 0, 0, 0);  // 12500*16B = 200000B exact
}

// ---------------- CSR build ----------------
__global__ __launch_bounds__(1024) void k_scan(const int* __restrict__ deg,
                                               int* __restrict__ offs,
                                               int* __restrict__ pos,
                                               float* __restrict__ invd) {
  __shared__ int sums[1024];
  const int tid = threadIdx.x;
  const int CH = 49;  // 1024*49 = 50176 >= 50000
  int lo = tid * CH;
  int hi = lo + CH; if (hi > N_NODES) hi = N_NODES;
  if (lo > N_NODES) lo = N_NODES;
  int s = 0;
  for (int i = lo; i < hi; ++i) s += deg[i];
  sums[tid] = s;
  __syncthreads();
  for (int off = 1; off < 1024; off <<= 1) {
    int t = (tid >= off) ? sums[tid - off] : 0;
    __syncthreads();
    sums[tid] += t;
    __syncthreads();
  }
  int run = sums[tid] - s;  // exclusive prefix of this chunk
  for (int i = lo; i < hi; ++i) {
    int d = deg[i];
    offs[i] = run; pos[i] = run;
    invd[i] = 1.0f / (float)((d > 1) ? d : 1);
    run += d;
  }
  if (tid == 1023) offs[N_NODES] = run;
}

// srcs stores src*DIM (u16-element offset) so gather skips the multiply
__global__ void k_scatter(const int* __restrict__ src, const int* __restrict__ dst,
                          int* __restrict__ pos, int* __restrict__ srcs) {
  int e = blockIdx.x * blockDim.x + threadIdx.x;
  if (e < N_EDGES) {
    int p = atomicAdd(&pos[dst[e]], 1);
    srcs[p] = src[e] * DIM;
  }
}

// ---------------- fused prep: cvt_x + edge histogram + 6x weight transpose ----
__global__ __launch_bounds__(256) void k_prep(
    const float* __restrict__ x, u16* __restrict__ xb,
    const int* __restrict__ dst, int* __restrict__ deg,
    const float* __restrict__ Wa, const float* __restrict__ Wb,
    const float* __restrict__ Wc, const float* __restrict__ Wd,
    const float* __restrict__ We, const float* __restrict__ Wf,
    u16* __restrict__ Oa, u16* __restrict__ Ob, u16* __restrict__ Oc,
    u16* __restrict__ Od, u16* __restrict__ Oe, u16* __restrict__ Of) {
  __shared__ u16 tbuf[64][66];
  const int t = blockIdx.x * 256 + threadIdx.x;

  // --- cvt_x: 8 floats -> 8 bf16 per thread ---
  const float4* p = (const float4*)(x + (size_t)t * 8);
  float4 a = p[0], b = p[1];
  uint4 o;
  o.x = (u32)f2bf(a.x) | ((u32)f2bf(a.y) << 16);
  o.y = (u32)f2bf(a.z) | ((u32)f2bf(a.w) << 16);
  o.z = (u32)f2bf(b.x) | ((u32)f2bf(b.y) << 16);
  o.w = (u32)f2bf(b.z) | ((u32)f2bf(b.w) << 16);
  *(uint4*)(xb + (size_t)t * 8) = o;

  // --- edge degree histogram ---
  if (t < N_EDGES) atomicAdd(&deg[dst[t]], 1);

  // --- weight transpose (last 384 blocks) ---
  const int wb = (int)blockIdx.x - (12500 - 384);
  if (wb >= 0) {
    const float* W; u16* O;
    switch (wb / 64) {
      case 0: W = Wa; O = Oa; break;
      case 1: W = Wb; O = Ob; break;
      case 2: W = Wc; O = Oc; break;
      case 3: W = Wd; O = Od; break;
      case 4: W = We; O = Oe; break;
      default: W = Wf; O = Of; break;
    }
    const int rem = wb & 63;
    const int k0 = (rem & 7) * 64, n0 = (rem >> 3) * 64;
    const int lr = threadIdx.x & 63, wr = threadIdx.x >> 6;
#pragma unroll
    for (int rr = 0; rr < 16; ++rr) {
      int k = k0 + wr * 16 + rr;
      tbuf[lr][wr * 16 + rr] = f2bf(W[(size_t)k * 512 + n0 + lr]);
    }
    __syncthreads();
#pragma unroll
    for (int rr = 0; rr < 16; ++rr) {
      int n = n0 + wr * 16 + rr;
      O[(size_t)n * 512 + k0 + lr] = tbuf[wr * 16 + rr][lr];
    }
  }
}

#define ACCB(A, q)                                              \
  A[0] += bf2f((q).x & 0xffff); A[1] += bf2f((u16)((q).x >> 16)); \
  A[2] += bf2f((q).y & 0xffff); A[3] += bf2f((u16)((q).y >> 16)); \
  A[4] += bf2f((q).z & 0xffff); A[5] += bf2f((u16)((q).z >> 16)); \
  A[6] += bf2f((q).w & 0xffff); A[7] += bf2f((u16)((q).w >> 16));

#define MFMA __builtin_amdgcn_mfma_f32_16x16x32_bf16

// ---------------- fused layer: gather -> LDS meanA, then dual-GEMM -----------
// BM=80 rows/block (625*80 = 50000 exact), BN=512 (A read once), 8 waves.
// Phase G: 8 waves x 10 nodes; mean rows -> meanA[80][512] bf16, chunk swizzle
//   slot = lane ^ (row&7)  (16B chunks; conflict-free write AND read).
// Phase K: 32 tiles of BK=32.  Tiles 0-15: A = meanA (ds_read, no staging),
//   B = WL.  Tiles 16-31: A = Ain fragments global->reg (1-tile prefetch),
//   B = WR.  B double-buffered in LDS via global_load_lds with SOURCE
//   pre-swizzle: slot(r,c) holds kchunk c ^ ((r>>1)&3)  (read slot%8 covers
//   all 8 bank groups -> conflict-free).  m97 schedule: vmcnt(0)+barrier/tile.
// LDS: meanA 81920 + B dbuf 65536 = 147456 B.
// MFMA K-chain order identical to the split kernels -> bit-identical output.
// EPI: 0 = relu -> bf16     1 = f32 (no relu) + bf16 copy
template <int EPI>
__global__ __launch_bounds__(512, 2) void k_fused(
    const u16* __restrict__ Ain, const u16* __restrict__ WL,
    const u16* __restrict__ WR, const int* __restrict__ offs,
    const int* __restrict__ srcs, const float* __restrict__ invd,
    const float* __restrict__ bias, float* __restrict__ outf,
    u16* __restrict__ outb) {
  __shared__ u16 meanA[80 * 512];     // 81920 B
  __shared__ u16 Bbuf[2][16384];      // 2 x 32768 B (512 rows x 4 x 16B chunks)
  const int tid = threadIdx.x;
  const int wid = tid >> 6, lane = tid & 63;
  const int row0 = (int)blockIdx.x * 80;

  // ---------------- gather phase: wave wid owns nodes wid*10 .. wid*10+9 ----
  const u16* hl = Ain + lane * 8;
  for (int j = 0; j < 10; ++j) {
    const int nl = wid * 10 + j;
    const int node = row0 + nl;              // always < 50000 (625*80 exact)
    const int s0 = offs[node], s1 = offs[node + 1];
    float ac0[8] = {0, 0, 0, 0, 0, 0, 0, 0};
    float ac1[8] = {0, 0, 0, 0, 0, 0, 0, 0};
    int i = s0;
    for (; i + 8 <= s1; i += 8) {
      int sa = srcs[i], sb = srcs[i + 1], sc = srcs[i + 2], sd = srcs[i + 3];
      int se = srcs[i + 4], sf = srcs[i + 5], sg = srcs[i + 6], sh = srcs[i + 7];
      uint4 qa = *(const uint4*)(hl + sa);
      uint4 qb = *(const uint4*)(hl + sb);
      uint4 qc = *(const uint4*)(hl + sc);
      uint4 qd = *(const uint4*)(hl + sd);
      uint4 qe = *(const uint4*)(hl + se);
      uint4 qf = *(const uint4*)(hl + sf);
      uint4 qg = *(const uint4*)(hl + sg);
      uint4 qh = *(const uint4*)(hl + sh);
      ACCB(ac0, qa) ACCB(ac1, qb) ACCB(ac0, qc) ACCB(ac1, qd)
      ACCB(ac0, qe) ACCB(ac1, qf) ACCB(ac0, qg) ACCB(ac1, qh)
    }
    if (i + 4 <= s1) {
      int sa = srcs[i], sb = srcs[i + 1], sc = srcs[i + 2], sd = srcs[i + 3];
      uint4 qa = *(const uint4*)(hl + sa);
      uint4 qb = *(const uint4*)(hl + sb);
      uint4 qc = *(const uint4*)(hl + sc);
      uint4 qd = *(const uint4*)(hl + sd);
      ACCB(ac0, qa) ACCB(ac1, qb) ACCB(ac0, qc) ACCB(ac1, qd)
      i += 4;
    }
    if (i + 2 <= s1) {
      int sa = srcs[i], sb = srcs[i + 1];
      uint4 qa = *(const uint4*)(hl + sa);
      uint4 qb = *(const uint4*)(hl + sb);
      ACCB(ac0, qa) ACCB(ac1, qb)
      i += 2;
    }
    if (i < s1) {
      int sa = srcs[i];
      uint4 qa = *(const uint4*)(hl + sa);
      ACCB(ac0, qa)
    }
    const float iv = invd[node];
#pragma unroll
    for (int k = 0; k < 8; ++k) ac0[k] = (ac0[k] + ac1[k]) * iv;
    uint4 w;
    w.x = (u32)f2bf(ac0[0]) | ((u32)f2bf(ac0[1]) << 16);
    w.y = (u32)f2bf(ac0[2]) | ((u32)f2bf(ac0[3]) << 16);
    w.z = (u32)f2bf(ac0[4]) | ((u32)f2bf(ac0[5]) << 16);
    w.w = (u32)f2bf(ac0[6]) | ((u32)f2bf(ac0[7]) << 16);
    *(uint4*)(meanA + (size_t)nl * 512 + ((lane ^ (nl & 7)) << 3)) = w;
  }

  // ---------------- GEMM phase ----------------
  f32x4 acc[5][4];
  const f32x4 z = {0.f, 0.f, 0.f, 0.f};
#pragma unroll
  for (int i = 0; i < 5; ++i)
#pragma unroll
    for (int j = 0; j < 4; ++j) acc[i][j] = z;

  // B staging: 4 wave-loads/ wave; slot(r,c) <- kchunk c ^ ((r>>1)&3)
  auto stageB = [&](int tt) {
    const u16* G = (tt < 16) ? WL : WR;
    const int kbase = (tt & 15) * 32;
    u16* dst0 = &Bbuf[tt & 1][0];
    const int swz = (lane & 3) ^ ((lane >> 3) & 3);  // src kchunk for this lane
#pragma unroll
    for (int p = 0; p < 4; ++p) {
      const int sb = (p * 8 + wid) * 64;             // wave-uniform slot base
      const int r = (sb >> 2) + (lane >> 2);
      const u16* g = G + (size_t)r * 512 + kbase + (swz << 3);
      __builtin_amdgcn_global_load_lds(
          (const __attribute__((address_space(1))) void*)g,
          (__attribute__((address_space(3))) void*)(dst0 + (size_t)sb * 8),
          16, 0, 0);
    }
  };

  uint4 aN[5], aC[5];
  auto loadA2 = [&](int tt) {  // tiles >=16: A fragments global -> regs
    const int kbase = (tt - 16) * 32 + ((lane >> 4) << 3);
#pragma unroll
    for (int i = 0; i < 5; ++i) {
      const int row = row0 + i * 16 + (lane & 15);
      aN[i] = *(const uint4*)(Ain + (size_t)row * 512 + kbase);
    }
  };

  stageB(0);

  for (int t = 0; t < 32; ++t) {
    asm volatile("s_waitcnt vmcnt(0)" ::: "memory");
    __builtin_amdgcn_s_barrier();
    asm volatile("" ::: "memory");
    if (t >= 16) {
#pragma unroll
      for (int i = 0; i < 5; ++i) aC[i] = aN[i];
    }
    if (t + 1 < 32) {
      stageB(t + 1);
      if (t + 1 >= 16) loadA2(t + 1);
    }

    bf16x8 aF[5], bF[4];
    const u16* Bt = &Bbuf[t & 1][0];
#pragma unroll
    for (int jg = 0; jg < 4; ++jg) {
      const int cc = wid * 64 + jg * 16 + (lane & 15);
      const int slot = cc * 4 + ((lane >> 4) ^ ((cc >> 1) & 3));
      bF[jg] = *(const bf16x8*)(Bt + (size_t)slot * 8);
    }
    if (t < 16) {
      const int kc = t * 4 + (lane >> 4);
#pragma unroll
      for (int ig = 0; ig < 5; ++ig) {
        const int r = ig * 16 + (lane & 15);
        aF[ig] = *(const bf16x8*)(meanA + (size_t)r * 512 + ((kc ^ (r & 7)) << 3));
      }
    } else {
#pragma unroll
      for (int ig = 0; ig < 5; ++ig) aF[ig] = *(const bf16x8*)&aC[ig];
    }
    __builtin_amdgcn_s_setprio(1);
#pragma unroll
    for (int ig = 0; ig < 5; ++ig)
#pragma unroll
      for (int jg = 0; jg < 4; ++jg)
        acc[ig][jg] = MFMA(aF[ig], bF[jg], acc[ig][jg], 0, 0, 0);
    __builtin_amdgcn_s_setprio(0);
  }

  // epilogue: row = row0 + ig*16 + (lane>>4)*4 + r ; col = wid*64 + jg*16 + (lane&15)
#pragma unroll
  for (int jg = 0; jg < 4; ++jg) {
    const int col = wid * 64 + jg * 16 + (lane & 15);
    const float bb = bias[col];
#pragma unroll
    for (int ig = 0; ig < 5; ++ig) {
      const int rbase = row0 + ig * 16 + ((lane >> 4) << 2);
      f32x4 v = acc[ig][jg];
#pragma unroll
      for (int r = 0; r < 4; ++r) {
        const int row = rbase + r;
        float f = v[r] + bb;
        if (EPI == 0) {
          f = fmaxf(f, 0.f);
          outb[(size_t)row * DIM + col] = f2bf(f);
        } else {
          outf[(size_t)row * DIM + col] = f;
          outb[(size_t)row * DIM + col] = f2bf(f);
        }
      }
    }
  }
}

// ---------------- heads GEMM: 112x512 tile, BK=64, 4-phase (unchanged) -------
#define BUFU 39936  // u16 per buffer: A 7168 + B 32768

template <int EPI>
__global__ __launch_bounds__(512, 2) void k_gemm112(
    const u16* __restrict__ A1, const u16* __restrict__ W1,
    const u16* __restrict__ A2, const u16* __restrict__ W2,
    const float* __restrict__ bias, const float* __restrict__ bias2,
    float* __restrict__ outf, float* __restrict__ outf2,
    u16* __restrict__ outb, int NT) {
  __shared__ u16 lds[2 * BUFU];  // 156 KB
  const int tid = threadIdx.x;
  const int wid = tid >> 6, lane = tid & 63;
  int head = 0, row0;
  if (EPI == 3) {
    head = (int)blockIdx.x & 1;
    row0 = ((int)blockIdx.x >> 1) * 112;
  } else {
    row0 = (int)blockIdx.x * 112;
  }
  const u16* BW = (EPI == 3) ? (head ? W2 : W1) : nullptr;

  f32x4 acc[7][4];
  const f32x4 z = {0.f, 0.f, 0.f, 0.f};
#pragma unroll
  for (int i = 0; i < 7; ++i)
#pragma unroll
    for (int j = 0; j < 4; ++j) acc[i][j] = z;

  const int ly = lane >> 3;
  const int schunk = (lane & 7) ^ ly;

  auto stageA = [&](int t, int h) {
    u16* tile = lds + (t & 1) * BUFU;
    const u16* G = (EPI == 3) ? A1 : ((t < 8) ? A1 : A2);
    int w = wid;
    if (h && w >= 6) w -= 2;
    const int rb = h * 64 + w * 8;
    int rg = row0 + rb + ly;
    if (rg > N_NODES - 1) rg = N_NODES - 1;
    const u16* g = G + (size_t)rg * 512 + (t & 7) * 64 + schunk * 8;
    __builtin_amdgcn_global_load_lds(
        (const __attribute__((address_space(1))) void*)g,
        (__attribute__((address_space(3))) void*)(tile + rb * 64), 16, 0, 0);
  };

  auto stageB = [&](int t, int jh) {
    u16* tile = lds + (t & 1) * BUFU + 7168;
    const u16* G = (EPI == 3) ? BW : ((t < 8) ? W1 : W2);
    const int kofs = (t & 7) * 64 + schunk * 8;
#pragma unroll
    for (int u = 0; u < 4; ++u) {
      const int rb = u * 128 + (wid >> 2) * 64 + (wid & 3) * 8 + jh * 32;
      const u16* g = G + (size_t)(rb + ly) * 512 + kofs;
      __builtin_amdgcn_global_load_lds(
          (const __attribute__((address_space(1))) void*)g,
          (__attribute__((address_space(3))) void*)(tile + rb * 64), 16, 0, 0);
    }
  };

  auto rdA = [&](const u16* T_, int ig, int kk) -> bf16x8 {
    const int r = ig * 16 + (lane & 15);
    const int off = ((kk * 4 + (lane >> 4)) ^ (lane & 7)) * 8;
    return *(const bf16x8*)(T_ + r * 64 + off);
  };
  auto rdB = [&](const u16* T_, int jg, int kk) -> bf16x8 {
    const int r = wid * 64 + jg * 16 + (lane & 15);
    const int off = ((kk * 4 + (lane >> 4)) ^ (lane & 7)) * 8;
    return *(const bf16x8*)(T_ + r * 64 + off);
  };

  stageA(0, 0); stageB(0, 0); stageB(0, 1); stageA(0, 1);

  for (int t = 0; t < NT; ++t) {
    const u16* At = lds + (t & 1) * BUFU;
    const u16* Bt = At + 7168;
    const bool more = (t + 1 < NT);
    bf16x8 aF[4][2], bF[2][2];

    asm volatile("s_waitcnt vmcnt(5)" ::: "memory");
    __builtin_amdgcn_s_barrier();
    asm volatile("" ::: "memory");
    if (more) stageA(t + 1, 0);
#pragma unroll
    for (int ip = 0; ip < 4; ++ip)
#pragma unroll
      for (int kk = 0; kk < 2; ++kk) aF[ip][kk] = rdA(At, ip, kk);
#pragma unroll
    for (int jp = 0; jp < 2; ++jp)
#pragma unroll
      for (int kk = 0; kk < 2; ++kk) bF[jp][kk] = rdB(Bt, jp, kk);
    __builtin_amdgcn_s_setprio(1);
#pragma unroll
    for (int ip = 0; ip < 4; ++ip)
#pragma unroll
      for (int jp = 0; jp < 2; ++jp)
#pragma unroll
        for (int kk = 0; kk < 2; ++kk)
          acc[ip][jp] = MFMA(aF[ip][kk], bF[jp][kk], acc[ip][jp], 0, 0, 0);
    __builtin_amdgcn_s_setprio(0);

    if (more) { asm volatile("s_waitcnt vmcnt(1)" ::: "memory"); }
    else      { asm volatile("s_waitcnt vmcnt(0)" ::: "memory"); }
    __builtin_amdgcn_s_barrier();
    asm volatile("" ::: "memory");
    if (more) stageB(t + 1, 0);
#pragma unroll
    for (int jp = 0; jp < 2; ++jp)
#pragma unroll
      for (int kk = 0; kk < 2; ++kk) bF[jp][kk] = rdB(Bt, 2 + jp, kk);
    __builtin_amdgcn_s_setprio(1);
#pragma unroll
    for (int ip = 0; ip < 4; ++ip)
#pragma unroll
      for (int jp = 0; jp < 2; ++jp)
#pragma unroll
        for (int kk = 0; kk < 2; ++kk)
          acc[ip][2 + jp] = MFMA(aF[ip][kk], bF[jp][kk], acc[ip][2 + jp], 0, 0, 0);
    __builtin_amdgcn_s_setprio(0);

    if (more) stageB(t + 1, 1);
#pragma unroll
    for (int ip = 0; ip < 3; ++ip)
#pragma unroll
      for (int kk = 0; kk < 2; ++kk) aF[ip][kk] = rdA(At, 4 + ip, kk);
    __builtin_amdgcn_s_setprio(1);
#pragma unroll
    for (int ip = 0; ip < 3; ++ip)
#pragma unroll
      for (int jp = 0; jp < 2; ++jp)
#pragma unroll
        for (int kk = 0; kk < 2; ++kk)
          acc[4 + ip][2 + jp] = MFMA(aF[ip][kk], bF[jp][kk], acc[4 + ip][2 + jp], 0, 0, 0);
    __builtin_amdgcn_s_setprio(0);

    if (more) stageA(t + 1, 1);
#pragma unroll
    for (int jp = 0; jp < 2; ++jp)
#pragma unroll
      for (int kk = 0; kk < 2; ++kk) bF[jp][kk] = rdB(Bt, jp, kk);
    __builtin_amdgcn_s_setprio(1);
#pragma unroll
    for (int ip = 0; ip < 3; ++ip)
#pragma unroll
      for (int jp = 0; jp < 2; ++jp)
#pragma unroll
        for (int kk = 0; kk < 2; ++kk)
          acc[4 + ip][jp] = MFMA(aF[ip][kk], bF[jp][kk], acc[4 + ip][jp], 0, 0, 0);
    __builtin_amdgcn_s_setprio(0);
  }

  const float* bs = (EPI == 3 && head) ? bias2 : bias;
  float* of = (EPI == 3 && head) ? outf2 : outf;
#pragma unroll
  for (int jg = 0; jg < 4; ++jg) {
    int col = wid * 64 + jg * 16 + (lane & 15);
    float bb = bs[col];
#pragma unroll
    for (int ig = 0; ig < 7; ++ig) {
      int rbase = row0 + ig * 16 + (lane >> 4) * 4;
      f32x4 v = acc[ig][jg];
#pragma unroll
      for (int r = 0; r < 4; ++r) {
        int row = rbase + r;
        if (row < N_NODES) {
          float f = v[r] + bb;
          if (EPI == 0) {
            f = fmaxf(f, 0.f);
            outb[(size_t)row * DIM + col] = f2bf(f);
          } else if (EPI == 1) {
            outf[(size_t)row * DIM + col] = f;
            outb[(size_t)row * DIM + col] = f2bf(f);
          } else {
            of[(size_t)row * DIM + col] = fmaxf(f, 0.f);
          }
        }
      }
    }
  }
}

// ---------------- launch ----------------
extern "C" void kernel_launch(void* const* d_in, const int* in_sizes, int n_in,
                              void* d_out, int out_size, void* d_ws, size_t ws_size,
                              hipStream_t stream) {
  (void)in_sizes; (void)n_in; (void)out_size; (void)ws_size;
  const float* x   = (const float*)d_in[0];
  const int*   ei  = (const int*)d_in[1];
  const float* Wl0 = (const float*)d_in[2];
  const float* bl0 = (const float*)d_in[3];
  const float* Wr0 = (const float*)d_in[4];
  const float* Wl1 = (const float*)d_in[5];
  const float* bl1 = (const float*)d_in[6];
  const float* Wr1 = (const float*)d_in[7];
  const float* Wv  = (const float*)d_in[8];
  const float* bv  = (const float*)d_in[9];
  const float* Wt  = (const float*)d_in[10];
  const float* bt  = (const float*)d_in[11];
  const int* srcI = ei;
  const int* dstI = ei + N_EDGES;

  float* out_h = (float*)d_out;
  float* out_v = out_h + (size_t)N_NODES * DIM;
  float* out_t = out_v + (size_t)N_NODES * DIM;
  u16* hrelub = (u16*)out_t;  // scratch: bf16 relu(h0) buffer (consumed pre-heads)

  uint8_t* p = (uint8_t*)d_ws;
  auto carve = [&](size_t bytes) -> uint8_t* {
    uint8_t* r = p; p += (bytes + 1023) & ~(size_t)1023; return r;
  };
  int*   deg  = (int*)carve((size_t)N_NODES * 4);
  int*   offs = (int*)carve((size_t)(N_NODES + 1) * 4);
  int*   pos  = (int*)carve((size_t)N_NODES * 4);
  float* invd = (float*)carve((size_t)N_NODES * 4);
  int*   srcs = (int*)carve((size_t)N_EDGES * 4);
  u16* Wl0b = (u16*)carve(512 * 512 * 2);
  u16* Wr0b = (u16*)carve(512 * 512 * 2);
  u16* Wl1b = (u16*)carve(512 * 512 * 2);
  u16* Wr1b = (u16*)carve(512 * 512 * 2);
  u16* Wvb  = (u16*)carve(512 * 512 * 2);
  u16* Wtb  = (u16*)carve(512 * 512 * 2);
  u16* xb   = (u16*)carve((size_t)N_NODES * DIM * 2);  // x bf16, later h bf16

  const int EB = (N_EDGES + 255) / 256;

  k_zero<<<49, 256, 0, stream>>>((int4*)deg);
  k_prep<<<12500, 256, 0, stream>>>(x, xb, dstI, deg,
                                    Wl0, Wr0, Wl1, Wr1, Wv, Wt,
                                    Wl0b, Wr0b, Wl1b, Wr1b, Wvb, Wtb);
  k_scan<<<1, 1024, 0, stream>>>(deg, offs, pos, invd);
  k_scatter<<<EB, 256, 0, stream>>>(srcI, dstI, pos, srcs);

  // layer 0 fused: gather(xb)+GEMM -> hrelub = relu(mean@Wl0 + x@Wr0 + bl0)
  k_fused<0><<<625, 512, 0, stream>>>(xb, Wl0b, Wr0b, offs, srcs, invd,
                                      bl0, nullptr, hrelub);
  // layer 1 fused: gather(hrelub)+GEMM -> out_h f32 + xb bf16
  k_fused<1><<<625, 512, 0, stream>>>(hrelub, Wl1b, Wr1b, offs, srcs, invd,
                                      bl1, out_h, xb);
  // fused heads: relu(h@Wv + bv) -> out_v ; relu(h@Wt + bt) -> out_t
  k_gemm112<3><<<896, 512, 0, stream>>>(xb, Wvb, nullptr, Wtb, bv, bt,
                                        out_v, out_t, nullptr, 8);
}

// Round 6
// 728.956 us; speedup vs baseline: 1.1351x; 1.1351x over previous
//
#include <hip/hip_runtime.h>
#include <hip/hip_bf16.h>
#include <stdint.h>

#define N_NODES 50000
#define N_EDGES 500000
#define DIM 512

typedef unsigned short u16;
typedef unsigned int u32;
typedef __bf16 bf16x8 __attribute__((ext_vector_type(8)));
typedef float f32x4 __attribute__((ext_vector_type(4)));

static __device__ __forceinline__ u16 f2bf(float f) {
  union { __bf16 b; u16 u; } cv; cv.b = (__bf16)f; return cv.u;
}
static __device__ __forceinline__ float bf2f(u16 u) {
  union { u16 u; __bf16 b; } cv; cv.u = u; return (float)cv.b;
}

// ---------------- deg zero (rocclr blit path avoided) ----------------
__global__ void k_zero(int4* __restrict__ deg4) {
  int t = blockIdx.x * 256 + threadIdx.x;
  if (t < 12500) deg4[t] = make_int4(0, 0, 0, 0);  // 12500*16B = 200000B exact
}

// ---------------- CSR build ----------------
__global__ __launch_bounds__(1024) void k_scan(const int* __restrict__ deg,
                                               int* __restrict__ offs,
                                               int* __restrict__ pos,
                                               float* __restrict__ invd) {
  __shared__ int sums[1024];
  const int tid = threadIdx.x;
  const int CH = 49;  // 1024*49 = 50176 >= 50000
  int lo = tid * CH;
  int hi = lo + CH; if (hi > N_NODES) hi = N_NODES;
  if (lo > N_NODES) lo = N_NODES;
  int s = 0;
  for (int i = lo; i < hi; ++i) s += deg[i];
  sums[tid] = s;
  __syncthreads();
  for (int off = 1; off < 1024; off <<= 1) {
    int t = (tid >= off) ? sums[tid - off] : 0;
    __syncthreads();
    sums[tid] += t;
    __syncthreads();
  }
  int run = sums[tid] - s;  // exclusive prefix of this chunk
  for (int i = lo; i < hi; ++i) {
    int d = deg[i];
    offs[i] = run; pos[i] = run;
    invd[i] = 1.0f / (float)((d > 1) ? d : 1);
    run += d;
  }
  if (tid == 1023) offs[N_NODES] = run;
}

// srcs stores src*DIM (u16-element offset) so gather skips the multiply
__global__ void k_scatter(const int* __restrict__ src, const int* __restrict__ dst,
                          int* __restrict__ pos, int* __restrict__ srcs) {
  int e = blockIdx.x * blockDim.x + threadIdx.x;
  if (e < N_EDGES) {
    int p = atomicAdd(&pos[dst[e]], 1);
    srcs[p] = src[e] * DIM;
  }
}

// ---------------- fused prep: cvt_x + edge histogram + 6x weight transpose ----
__global__ __launch_bounds__(256) void k_prep(
    const float* __restrict__ x, u16* __restrict__ xb,
    const int* __restrict__ dst, int* __restrict__ deg,
    const float* __restrict__ Wa, const float* __restrict__ Wb,
    const float* __restrict__ Wc, const float* __restrict__ Wd,
    const float* __restrict__ We, const float* __restrict__ Wf,
    u16* __restrict__ Oa, u16* __restrict__ Ob, u16* __restrict__ Oc,
    u16* __restrict__ Od, u16* __restrict__ Oe, u16* __restrict__ Of) {
  __shared__ u16 tbuf[64][66];
  const int t = blockIdx.x * 256 + threadIdx.x;

  // --- cvt_x: 8 floats -> 8 bf16 per thread ---
  const float4* p = (const float4*)(x + (size_t)t * 8);
  float4 a = p[0], b = p[1];
  uint4 o;
  o.x = (u32)f2bf(a.x) | ((u32)f2bf(a.y) << 16);
  o.y = (u32)f2bf(a.z) | ((u32)f2bf(a.w) << 16);
  o.z = (u32)f2bf(b.x) | ((u32)f2bf(b.y) << 16);
  o.w = (u32)f2bf(b.z) | ((u32)f2bf(b.w) << 16);
  *(uint4*)(xb + (size_t)t * 8) = o;

  // --- edge degree histogram ---
  if (t < N_EDGES) atomicAdd(&deg[dst[t]], 1);

  // --- weight transpose (last 384 blocks) ---
  const int wb = (int)blockIdx.x - (12500 - 384);
  if (wb >= 0) {
    const float* W; u16* O;
    switch (wb / 64) {
      case 0: W = Wa; O = Oa; break;
      case 1: W = Wb; O = Ob; break;
      case 2: W = Wc; O = Oc; break;
      case 3: W = Wd; O = Od; break;
      case 4: W = We; O = Oe; break;
      default: W = Wf; O = Of; break;
    }
    const int rem = wb & 63;
    const int k0 = (rem & 7) * 64, n0 = (rem >> 3) * 64;
    const int lr = threadIdx.x & 63, wr = threadIdx.x >> 6;
#pragma unroll
    for (int rr = 0; rr < 16; ++rr) {
      int k = k0 + wr * 16 + rr;
      tbuf[lr][wr * 16 + rr] = f2bf(W[(size_t)k * 512 + n0 + lr]);
    }
    __syncthreads();
#pragma unroll
    for (int rr = 0; rr < 16; ++rr) {
      int n = n0 + wr * 16 + rr;
      O[(size_t)n * 512 + k0 + lr] = tbuf[wr * 16 + rr][lr];
    }
  }
}

// ---------------- aggregation: one wave per node, bf16 gather (r4-proven) ----
#define ACCB(A, q)                                              \
  A[0] += bf2f((q).x & 0xffff); A[1] += bf2f((u16)((q).x >> 16)); \
  A[2] += bf2f((q).y & 0xffff); A[3] += bf2f((u16)((q).y >> 16)); \
  A[4] += bf2f((q).z & 0xffff); A[5] += bf2f((u16)((q).z >> 16)); \
  A[6] += bf2f((q).w & 0xffff); A[7] += bf2f((u16)((q).w >> 16));

__global__ __launch_bounds__(256) void k_agg_bf16(
    const u16* __restrict__ hb, const int* __restrict__ offs,
    const int* __restrict__ srcs, const float* __restrict__ invd,
    u16* __restrict__ outb) {
  int node = blockIdx.x * 4 + (threadIdx.x >> 6);
  int lane = threadIdx.x & 63;
  if (node >= N_NODES) return;
  int s0 = offs[node], s1 = offs[node + 1];
  float acc[8] = {0, 0, 0, 0, 0, 0, 0, 0};
  float acd[8] = {0, 0, 0, 0, 0, 0, 0, 0};
  const u16* hl = hb + lane * 8;
  int i = s0;
  for (; i + 8 <= s1; i += 8) {
    int sa = srcs[i], sb = srcs[i + 1], sc = srcs[i + 2], sd = srcs[i + 3];
    int se = srcs[i + 4], sf = srcs[i + 5], sg = srcs[i + 6], sh = srcs[i + 7];
    uint4 qa = *(const uint4*)(hl + sa);
    uint4 qb = *(const uint4*)(hl + sb);
    uint4 qc = *(const uint4*)(hl + sc);
    uint4 qd = *(const uint4*)(hl + sd);
    uint4 qe = *(const uint4*)(hl + se);
    uint4 qf = *(const uint4*)(hl + sf);
    uint4 qg = *(const uint4*)(hl + sg);
    uint4 qh = *(const uint4*)(hl + sh);
    ACCB(acc, qa) ACCB(acd, qb) ACCB(acc, qc) ACCB(acd, qd)
    ACCB(acc, qe) ACCB(acd, qf) ACCB(acc, qg) ACCB(acd, qh)
  }
  if (i + 4 <= s1) {
    int sa = srcs[i], sb = srcs[i + 1], sc = srcs[i + 2], sd = srcs[i + 3];
    uint4 qa = *(const uint4*)(hl + sa);
    uint4 qb = *(const uint4*)(hl + sb);
    uint4 qc = *(const uint4*)(hl + sc);
    uint4 qd = *(const uint4*)(hl + sd);
    ACCB(acc, qa) ACCB(acd, qb) ACCB(acc, qc) ACCB(acd, qd)
    i += 4;
  }
  if (i + 2 <= s1) {
    int sa = srcs[i], sb = srcs[i + 1];
    uint4 qa = *(const uint4*)(hl + sa);
    uint4 qb = *(const uint4*)(hl + sb);
    ACCB(acc, qa) ACCB(acd, qb)
    i += 2;
  }
  if (i < s1) {
    int sa = srcs[i];
    uint4 qa = *(const uint4*)(hl + sa);
    ACCB(acc, qa)
  }
  float iv = invd[node];
#pragma unroll
  for (int k = 0; k < 8; ++k) acc[k] = (acc[k] + acd[k]) * iv;
  uint4 o;
  o.x = (u32)f2bf(acc[0]) | ((u32)f2bf(acc[1]) << 16);
  o.y = (u32)f2bf(acc[2]) | ((u32)f2bf(acc[3]) << 16);
  o.z = (u32)f2bf(acc[4]) | ((u32)f2bf(acc[5]) << 16);
  o.w = (u32)f2bf(acc[6]) | ((u32)f2bf(acc[7]) << 16);
  *(uint4*)(outb + (size_t)node * DIM + lane * 8) = o;
}

// ---------------- GEMM: 80x512 tile, BK=32, 2-phase (k_fused-phase structure) -
// C[M,512] = A1@W1t (+ A2@W2t) + bias.  A row-major [M,512] bf16; W [N][K] bf16.
// Grid 625 (625*80 = 50000 exact, no row clamps; heads 1250 = x2).
// 8 waves; wave w owns cols [w*64, w*64+63]; acc[5][4].
// LDS 74KB: A dbuf 2x(80x32) + B dbuf 2x(512x32), both staged by
// global_load_lds with SOURCE chunk pre-swizzle swz=(lane&3)^((lane>>3)&3);
// read slot = kc ^ ((row>>1)&3)  (<=2-way bank aliasing = free).
// Schedule per tile: vmcnt(0); barrier; stage t+1 (other buffer); ds-read
// aF/bF of t; 20 MFMA.  K-order sequential -> bit-identical to prior kernels.
// EPI: 0 = relu->bf16   1 = f32 + bf16 copy   3 = dual-head relu->f32
#define MFMA __builtin_amdgcn_mfma_f32_16x16x32_bf16

template <int EPI>
__global__ __launch_bounds__(512, 2) void k_g2(
    const u16* __restrict__ A1, const u16* __restrict__ W1,
    const u16* __restrict__ A2, const u16* __restrict__ W2,
    const float* __restrict__ bias, const float* __restrict__ bias2,
    float* __restrict__ outf, float* __restrict__ outf2,
    u16* __restrict__ outb, int NT) {
  __shared__ u16 Abuf[2][2560];    // 80 rows x 4 slots x 8 u16
  __shared__ u16 Bbuf[2][16384];   // 512 rows x 4 slots x 8 u16
  const int tid = threadIdx.x;
  const int wid = tid >> 6, lane = tid & 63;
  int head = 0, row0;
  if (EPI == 3) {
    head = (int)blockIdx.x & 1;
    row0 = ((int)blockIdx.x >> 1) * 80;
  } else {
    row0 = (int)blockIdx.x * 80;
  }
  const u16* BW = (EPI == 3) ? (head ? W2 : W1) : nullptr;

  f32x4 acc[5][4];
  const f32x4 z = {0.f, 0.f, 0.f, 0.f};
#pragma unroll
  for (int i = 0; i < 5; ++i)
#pragma unroll
    for (int j = 0; j < 4; ++j) acc[i][j] = z;

  const int swz = (lane & 3) ^ ((lane >> 3) & 3);  // source k-chunk pre-swizzle

  // A tile 80x32: waves 0-4 stage one 1KB load each (slots wid*64 .. +63)
  auto stageA = [&](int t) {
    if (wid < 5) {
      const u16* G = (EPI == 3) ? A1 : ((t < 16) ? A1 : A2);
      const int r = wid * 16 + (lane >> 2);  // row 0..79 (per-lane source row)
      const u16* g = G + (size_t)(row0 + r) * 512 + (t & 15) * 32 + (swz << 3);
      __builtin_amdgcn_global_load_lds(
          (const __attribute__((address_space(1))) void*)g,
          (__attribute__((address_space(3))) void*)(&Abuf[t & 1][0] +
                                                    (size_t)(wid * 64) * 8),
          16, 0, 0);
    }
  };

  // B tile 512x32: 8 waves x 4 loads (k_fused-verified pattern)
  auto stageB = [&](int t) {
    const u16* G = (EPI == 3) ? BW : ((t < 16) ? W1 : W2);
    const int kbase = (t & 15) * 32;
    u16* dst0 = &Bbuf[t & 1][0];
#pragma unroll
    for (int p = 0; p < 4; ++p) {
      const int sb = (p * 8 + wid) * 64;      // wave-uniform slot base
      const int r = (sb >> 2) + (lane >> 2);  // per-lane source row
      const u16* g = G + (size_t)r * 512 + kbase + (swz << 3);
      __builtin_amdgcn_global_load_lds(
          (const __attribute__((address_space(1))) void*)g,
          (__attribute__((address_space(3))) void*)(dst0 + (size_t)sb * 8),
          16, 0, 0);
    }
  };

  auto rdA = [&](const u16* T_, int ig) -> bf16x8 {
    const int r = ig * 16 + (lane & 15);
    const int slot = (lane >> 4) ^ ((r >> 1) & 3);
    return *(const bf16x8*)(T_ + r * 32 + slot * 8);
  };
  auto rdB = [&](const u16* T_, int jg) -> bf16x8 {
    const int cc = wid * 64 + jg * 16 + (lane & 15);
    const int slot = (lane >> 4) ^ ((cc >> 1) & 3);
    return *(const bf16x8*)(T_ + cc * 32 + slot * 8);
  };

  stageA(0); stageB(0);

  for (int t = 0; t < NT; ++t) {
    asm volatile("s_waitcnt vmcnt(0)" ::: "memory");
    __builtin_amdgcn_s_barrier();
    asm volatile("" ::: "memory");
    if (t + 1 < NT) { stageA(t + 1); stageB(t + 1); }

    bf16x8 aF[5], bF[4];
    const u16* At = &Abuf[t & 1][0];
    const u16* Bt = &Bbuf[t & 1][0];
#pragma unroll
    for (int ig = 0; ig < 5; ++ig) aF[ig] = rdA(At, ig);
#pragma unroll
    for (int jg = 0; jg < 4; ++jg) bF[jg] = rdB(Bt, jg);
    __builtin_amdgcn_s_setprio(1);
#pragma unroll
    for (int ig = 0; ig < 5; ++ig)
#pragma unroll
      for (int jg = 0; jg < 4; ++jg)
        acc[ig][jg] = MFMA(aF[ig], bF[jg], acc[ig][jg], 0, 0, 0);
    __builtin_amdgcn_s_setprio(0);
  }

  // epilogue: row = row0 + ig*16 + (lane>>4)*4 + r ; col = wid*64 + jg*16 + (lane&15)
  const float* bs = (EPI == 3 && head) ? bias2 : bias;
  float* of = (EPI == 3 && head) ? outf2 : outf;
#pragma unroll
  for (int jg = 0; jg < 4; ++jg) {
    const int col = wid * 64 + jg * 16 + (lane & 15);
    const float bb = bs[col];
#pragma unroll
    for (int ig = 0; ig < 5; ++ig) {
      const int rbase = row0 + ig * 16 + ((lane >> 4) << 2);
      f32x4 v = acc[ig][jg];
#pragma unroll
      for (int r = 0; r < 4; ++r) {
        const int row = rbase + r;  // < 50000 always (625*80 exact)
        float f = v[r] + bb;
        if (EPI == 0) {
          f = fmaxf(f, 0.f);
          outb[(size_t)row * DIM + col] = f2bf(f);
        } else if (EPI == 1) {
          outf[(size_t)row * DIM + col] = f;
          outb[(size_t)row * DIM + col] = f2bf(f);
        } else {
          of[(size_t)row * DIM + col] = fmaxf(f, 0.f);
        }
      }
    }
  }
}

// ---------------- launch ----------------
extern "C" void kernel_launch(void* const* d_in, const int* in_sizes, int n_in,
                              void* d_out, int out_size, void* d_ws, size_t ws_size,
                              hipStream_t stream) {
  (void)in_sizes; (void)n_in; (void)out_size; (void)ws_size;
  const float* x   = (const float*)d_in[0];
  const int*   ei  = (const int*)d_in[1];
  const float* Wl0 = (const float*)d_in[2];
  const float* bl0 = (const float*)d_in[3];
  const float* Wr0 = (const float*)d_in[4];
  const float* Wl1 = (const float*)d_in[5];
  const float* bl1 = (const float*)d_in[6];
  const float* Wr1 = (const float*)d_in[7];
  const float* Wv  = (const float*)d_in[8];
  const float* bv  = (const float*)d_in[9];
  const float* Wt  = (const float*)d_in[10];
  const float* bt  = (const float*)d_in[11];
  const int* srcI = ei;
  const int* dstI = ei + N_EDGES;

  float* out_h = (float*)d_out;
  float* out_v = out_h + (size_t)N_NODES * DIM;
  float* out_t = out_v + (size_t)N_NODES * DIM;
  u16* meanb  = (u16*)out_v;  // scratch: bf16 mean buffer (consumed before final write)
  u16* hrelub = (u16*)out_t;  // scratch: bf16 relu(h0) buffer

  uint8_t* p = (uint8_t*)d_ws;
  auto carve = [&](size_t bytes) -> uint8_t* {
    uint8_t* r = p; p += (bytes + 1023) & ~(size_t)1023; return r;
  };
  int*   deg  = (int*)carve((size_t)N_NODES * 4);
  int*   offs = (int*)carve((size_t)(N_NODES + 1) * 4);
  int*   pos  = (int*)carve((size_t)N_NODES * 4);
  float* invd = (float*)carve((size_t)N_NODES * 4);
  int*   srcs = (int*)carve((size_t)N_EDGES * 4);
  u16* Wl0b = (u16*)carve(512 * 512 * 2);
  u16* Wr0b = (u16*)carve(512 * 512 * 2);
  u16* Wl1b = (u16*)carve(512 * 512 * 2);
  u16* Wr1b = (u16*)carve(512 * 512 * 2);
  u16* Wvb  = (u16*)carve(512 * 512 * 2);
  u16* Wtb  = (u16*)carve(512 * 512 * 2);
  u16* xb   = (u16*)carve((size_t)N_NODES * DIM * 2);  // x bf16, later h bf16

  const int EB = (N_EDGES + 255) / 256;

  k_zero<<<49, 256, 0, stream>>>((int4*)deg);
  k_prep<<<12500, 256, 0, stream>>>(x, xb, dstI, deg,
                                    Wl0, Wr0, Wl1, Wr1, Wv, Wt,
                                    Wl0b, Wr0b, Wl1b, Wr1b, Wvb, Wtb);
  k_scan<<<1, 1024, 0, stream>>>(deg, offs, pos, invd);
  k_scatter<<<EB, 256, 0, stream>>>(srcI, dstI, pos, srcs);

  // layer 0: mean-agg(xb) -> meanb ; h0 = relu(mean@Wl0 + x@Wr0 + bl0) -> hrelub
  k_agg_bf16<<<12500, 256, 0, stream>>>(xb, offs, srcs, invd, meanb);
  k_g2<0><<<625, 512, 0, stream>>>(meanb, Wl0b, xb, Wr0b, bl0, nullptr,
                                   nullptr, nullptr, hrelub, 32);

  // layer 1: mean-agg(hrelub) -> meanb ; h = mean@Wl1 + h0@Wr1 + bl1 -> out_h + xb
  k_agg_bf16<<<12500, 256, 0, stream>>>(hrelub, offs, srcs, invd, meanb);
  k_g2<1><<<625, 512, 0, stream>>>(meanb, Wl1b, hrelub, Wr1b, bl1, nullptr,
                                   out_h, nullptr, xb, 32);

  // fused heads: relu(h@Wv + bv) -> out_v ; relu(h@Wt + bt) -> out_t
  k_g2<3><<<1250, 512, 0, stream>>>(xb, Wvb, nullptr, Wtb, bv, bt,
                                    out_v, out_t, nullptr, 16);
}

// Round 7
// 646.641 us; speedup vs baseline: 1.2796x; 1.1273x over previous
//
#include <hip/hip_runtime.h>
#include <hip/hip_bf16.h>
#include <stdint.h>

#define N_NODES 50000
#define N_EDGES 500000
#define DIM 512

typedef unsigned short u16;
typedef unsigned int u32;
typedef __bf16 bf16x8 __attribute__((ext_vector_type(8)));
typedef float f32x4 __attribute__((ext_vector_type(4)));

static __device__ __forceinline__ u16 f2bf(float f) {
  union { __bf16 b; u16 u; } cv; cv.b = (__bf16)f; return cv.u;
}
static __device__ __forceinline__ float bf2f(u16 u) {
  union { u16 u; __bf16 b; } cv; cv.u = u; return (float)cv.b;
}

// ---------------- deg zero (rocclr blit path avoided) ----------------
__global__ void k_zero(int4* __restrict__ deg4) {
  int t = blockIdx.x * 256 + threadIdx.x;
  if (t < 12500) deg4[t] = make_int4(0, 0, 0, 0);  // 12500*16B = 200000B exact
}

// ---------------- CSR build ----------------
__global__ __launch_bounds__(1024) void k_scan(const int* __restrict__ deg,
                                               int* __restrict__ offs,
                                               int* __restrict__ pos,
                                               float* __restrict__ invd) {
  __shared__ int sums[1024];
  const int tid = threadIdx.x;
  const int CH = 49;  // 1024*49 = 50176 >= 50000
  int lo = tid * CH;
  int hi = lo + CH; if (hi > N_NODES) hi = N_NODES;
  if (lo > N_NODES) lo = N_NODES;
  int s = 0;
  for (int i = lo; i < hi; ++i) s += deg[i];
  sums[tid] = s;
  __syncthreads();
  for (int off = 1; off < 1024; off <<= 1) {
    int t = (tid >= off) ? sums[tid - off] : 0;
    __syncthreads();
    sums[tid] += t;
    __syncthreads();
  }
  int run = sums[tid] - s;  // exclusive prefix of this chunk
  for (int i = lo; i < hi; ++i) {
    int d = deg[i];
    offs[i] = run; pos[i] = run;
    invd[i] = 1.0f / (float)((d > 1) ? d : 1);
    run += d;
  }
  if (tid == 1023) offs[N_NODES] = run;
}

// srcs stores src*DIM (u16-element offset) so gather skips the multiply
__global__ void k_scatter(const int* __restrict__ src, const int* __restrict__ dst,
                          int* __restrict__ pos, int* __restrict__ srcs) {
  int e = blockIdx.x * blockDim.x + threadIdx.x;
  if (e < N_EDGES) {
    int p = atomicAdd(&pos[dst[e]], 1);
    srcs[p] = src[e] * DIM;
  }
}

// ---------------- fused prep: cvt_x + edge histogram + 6x weight transpose ----
__global__ __launch_bounds__(256) void k_prep(
    const float* __restrict__ x, u16* __restrict__ xb,
    const int* __restrict__ dst, int* __restrict__ deg,
    const float* __restrict__ Wa, const float* __restrict__ Wb,
    const float* __restrict__ Wc, const float* __restrict__ Wd,
    const float* __restrict__ We, const float* __restrict__ Wf,
    u16* __restrict__ Oa, u16* __restrict__ Ob, u16* __restrict__ Oc,
    u16* __restrict__ Od, u16* __restrict__ Oe, u16* __restrict__ Of) {
  __shared__ u16 tbuf[64][66];
  const int t = blockIdx.x * 256 + threadIdx.x;

  // --- cvt_x: 8 floats -> 8 bf16 per thread ---
  const float4* p = (const float4*)(x + (size_t)t * 8);
  float4 a = p[0], b = p[1];
  uint4 o;
  o.x = (u32)f2bf(a.x) | ((u32)f2bf(a.y) << 16);
  o.y = (u32)f2bf(a.z) | ((u32)f2bf(a.w) << 16);
  o.z = (u32)f2bf(b.x) | ((u32)f2bf(b.y) << 16);
  o.w = (u32)f2bf(b.z) | ((u32)f2bf(b.w) << 16);
  *(uint4*)(xb + (size_t)t * 8) = o;

  // --- edge degree histogram ---
  if (t < N_EDGES) atomicAdd(&deg[dst[t]], 1);

  // --- weight transpose (last 384 blocks) ---
  const int wb = (int)blockIdx.x - (12500 - 384);
  if (wb >= 0) {
    const float* W; u16* O;
    switch (wb / 64) {
      case 0: W = Wa; O = Oa; break;
      case 1: W = Wb; O = Ob; break;
      case 2: W = Wc; O = Oc; break;
      case 3: W = Wd; O = Od; break;
      case 4: W = We; O = Oe; break;
      default: W = Wf; O = Of; break;
    }
    const int rem = wb & 63;
    const int k0 = (rem & 7) * 64, n0 = (rem >> 3) * 64;
    const int lr = threadIdx.x & 63, wr = threadIdx.x >> 6;
#pragma unroll
    for (int rr = 0; rr < 16; ++rr) {
      int k = k0 + wr * 16 + rr;
      tbuf[lr][wr * 16 + rr] = f2bf(W[(size_t)k * 512 + n0 + lr]);
    }
    __syncthreads();
#pragma unroll
    for (int rr = 0; rr < 16; ++rr) {
      int n = n0 + wr * 16 + rr;
      O[(size_t)n * 512 + k0 + lr] = tbuf[wr * 16 + rr][lr];
    }
  }
}

// ---------------- aggregation: one wave per node, bf16 gather ----------------
// 8-wide edge unroll, two accumulator banks (r4-measured best: 107 us/pass,
// ~5.3 TB/s effective random-row gather = fabric floor; deeper MLP is null).
#define ACCB(A, q)                                              \
  A[0] += bf2f((q).x & 0xffff); A[1] += bf2f((u16)((q).x >> 16)); \
  A[2] += bf2f((q).y & 0xffff); A[3] += bf2f((u16)((q).y >> 16)); \
  A[4] += bf2f((q).z & 0xffff); A[5] += bf2f((u16)((q).z >> 16)); \
  A[6] += bf2f((q).w & 0xffff); A[7] += bf2f((u16)((q).w >> 16));

__global__ __launch_bounds__(256) void k_agg_bf16(
    const u16* __restrict__ hb, const int* __restrict__ offs,
    const int* __restrict__ srcs, const float* __restrict__ invd,
    u16* __restrict__ outb) {
  int node = blockIdx.x * 4 + (threadIdx.x >> 6);
  int lane = threadIdx.x & 63;
  if (node >= N_NODES) return;
  int s0 = offs[node], s1 = offs[node + 1];
  float acc[8] = {0, 0, 0, 0, 0, 0, 0, 0};
  float acd[8] = {0, 0, 0, 0, 0, 0, 0, 0};
  const u16* hl = hb + lane * 8;
  int i = s0;
  for (; i + 8 <= s1; i += 8) {
    int sa = srcs[i], sb = srcs[i + 1], sc = srcs[i + 2], sd = srcs[i + 3];
    int se = srcs[i + 4], sf = srcs[i + 5], sg = srcs[i + 6], sh = srcs[i + 7];
    uint4 qa = *(const uint4*)(hl + sa);
    uint4 qb = *(const uint4*)(hl + sb);
    uint4 qc = *(const uint4*)(hl + sc);
    uint4 qd = *(const uint4*)(hl + sd);
    uint4 qe = *(const uint4*)(hl + se);
    uint4 qf = *(const uint4*)(hl + sf);
    uint4 qg = *(const uint4*)(hl + sg);
    uint4 qh = *(const uint4*)(hl + sh);
    ACCB(acc, qa) ACCB(acd, qb) ACCB(acc, qc) ACCB(acd, qd)
    ACCB(acc, qe) ACCB(acd, qf) ACCB(acc, qg) ACCB(acd, qh)
  }
  if (i + 4 <= s1) {
    int sa = srcs[i], sb = srcs[i + 1], sc = srcs[i + 2], sd = srcs[i + 3];
    uint4 qa = *(const uint4*)(hl + sa);
    uint4 qb = *(const uint4*)(hl + sb);
    uint4 qc = *(const uint4*)(hl + sc);
    uint4 qd = *(const uint4*)(hl + sd);
    ACCB(acc, qa) ACCB(acd, qb) ACCB(acc, qc) ACCB(acd, qd)
    i += 4;
  }
  if (i + 2 <= s1) {
    int sa = srcs[i], sb = srcs[i + 1];
    uint4 qa = *(const uint4*)(hl + sa);
    uint4 qb = *(const uint4*)(hl + sb);
    ACCB(acc, qa) ACCB(acd, qb)
    i += 2;
  }
  if (i < s1) {
    int sa = srcs[i];
    uint4 qa = *(const uint4*)(hl + sa);
    ACCB(acc, qa)
  }
  float iv = invd[node];
#pragma unroll
  for (int k = 0; k < 8; ++k) acc[k] = (acc[k] + acd[k]) * iv;
  uint4 o;
  o.x = (u32)f2bf(acc[0]) | ((u32)f2bf(acc[1]) << 16);
  o.y = (u32)f2bf(acc[2]) | ((u32)f2bf(acc[3]) << 16);
  o.z = (u32)f2bf(acc[4]) | ((u32)f2bf(acc[5]) << 16);
  o.w = (u32)f2bf(acc[6]) | ((u32)f2bf(acc[7]) << 16);
  *(uint4*)(outb + (size_t)node * DIM + lane * 8) = o;
}

// ---------------- GEMM: 112x512 tile, BK=64, 8 waves, 4-phase pipeline --------
// Best-measured structure (r4, 646.7 us pipeline): counted vmcnt (T4),
// XOR-chunk LDS swizzle (T2), setprio (T5), 4-phase interleave (T3-lite).
// r6 proved a 2-phase vmcnt(0) replacement costs +82 us (m233 stall class).
// C[M,512] = A1@W1t (+ A2@W2t) + bias.  A row-major [M,512] bf16;
// W pre-transposed [Nout=512][K=512] bf16.  BN=512 => A read ONCE.
// Grid: M/112 = 448 exact row tiles (x2 for dual-head EPI 3).
// LDS 156KB: 2 buffers x (A 112x64 + B 512x64) bf16, XOR-chunk swizzle.
// Per-tile issue order (per wave, 10 global_load_lds):
//   A-h0(1), B-jh0(4), B-jh1(4), A-h1(1; waves 6,7 duplicate rows 96..111)
// Waits: ph1 vmcnt(5); ph2 vmcnt(1|0).
// EPI: 0 = relu -> bf16   1 = f32 + bf16 copy (no relu)
// EPI 3 = fused dual-head: head = bx&1 selects (W2,bias2,outf2); relu -> f32.
#define MFMA __builtin_amdgcn_mfma_f32_16x16x32_bf16
#define BUFU 39936  // u16 per buffer: A 7168 + B 32768

template <int EPI>
__global__ __launch_bounds__(512, 2) void k_gemm112(
    const u16* __restrict__ A1, const u16* __restrict__ W1,
    const u16* __restrict__ A2, const u16* __restrict__ W2,
    const float* __restrict__ bias, const float* __restrict__ bias2,
    float* __restrict__ outf, float* __restrict__ outf2,
    u16* __restrict__ outb, int NT) {
  __shared__ u16 lds[2 * BUFU];  // 156 KB
  const int tid = threadIdx.x;
  const int wid = tid >> 6, lane = tid & 63;
  int head = 0, row0;
  if (EPI == 3) {
    head = (int)blockIdx.x & 1;
    row0 = ((int)blockIdx.x >> 1) * 112;
  } else {
    row0 = (int)blockIdx.x * 112;
  }
  const u16* BW = (EPI == 3) ? (head ? W2 : W1) : nullptr;

  f32x4 acc[7][4];
  const f32x4 z = {0.f, 0.f, 0.f, 0.f};
#pragma unroll
  for (int i = 0; i < 7; ++i)
#pragma unroll
    for (int j = 0; j < 4; ++j) acc[i][j] = z;

  const int ly = lane >> 3;
  const int schunk = (lane & 7) ^ ly;

  auto stageA = [&](int t, int h) {
    u16* tile = lds + (t & 1) * BUFU;
    const u16* G = (EPI == 3) ? A1 : ((t < 8) ? A1 : A2);
    int w = wid;
    if (h && w >= 6) w -= 2;  // duplicate rows 96..111 (same src+dest, benign)
    const int rb = h * 64 + w * 8;
    int rg = row0 + rb + ly;
    if (rg > N_NODES - 1) rg = N_NODES - 1;
    const u16* g = G + (size_t)rg * 512 + (t & 7) * 64 + schunk * 8;
    __builtin_amdgcn_global_load_lds(
        (const __attribute__((address_space(1))) void*)g,
        (__attribute__((address_space(3))) void*)(tile + rb * 64), 16, 0, 0);
  };

  auto stageB = [&](int t, int jh) {
    u16* tile = lds + (t & 1) * BUFU + 7168;
    const u16* G = (EPI == 3) ? BW : ((t < 8) ? W1 : W2);
    const int kofs = (t & 7) * 64 + schunk * 8;
#pragma unroll
    for (int u = 0; u < 4; ++u) {
      const int rb = u * 128 + (wid >> 2) * 64 + (wid & 3) * 8 + jh * 32;
      const u16* g = G + (size_t)(rb + ly) * 512 + kofs;
      __builtin_amdgcn_global_load_lds(
          (const __attribute__((address_space(1))) void*)g,
          (__attribute__((address_space(3))) void*)(tile + rb * 64), 16, 0, 0);
    }
  };

  auto rdA = [&](const u16* T_, int ig, int kk) -> bf16x8 {
    const int r = ig * 16 + (lane & 15);
    const int off = ((kk * 4 + (lane >> 4)) ^ (lane & 7)) * 8;
    return *(const bf16x8*)(T_ + r * 64 + off);
  };
  auto rdB = [&](const u16* T_, int jg, int kk) -> bf16x8 {
    const int r = wid * 64 + jg * 16 + (lane & 15);
    const int off = ((kk * 4 + (lane >> 4)) ^ (lane & 7)) * 8;
    return *(const bf16x8*)(T_ + r * 64 + off);
  };

  stageA(0, 0); stageB(0, 0); stageB(0, 1); stageA(0, 1);

  for (int t = 0; t < NT; ++t) {
    const u16* At = lds + (t & 1) * BUFU;
    const u16* Bt = At + 7168;
    const bool more = (t + 1 < NT);
    bf16x8 aF[4][2], bF[2][2];

    // ---- phase 1: (ig 0-3, jg 0-1); needs A-h0 + B-jh0 ----
    asm volatile("s_waitcnt vmcnt(5)" ::: "memory");
    __builtin_amdgcn_s_barrier();
    asm volatile("" ::: "memory");
    if (more) stageA(t + 1, 0);
#pragma unroll
    for (int ip = 0; ip < 4; ++ip)
#pragma unroll
      for (int kk = 0; kk < 2; ++kk) aF[ip][kk] = rdA(At, ip, kk);
#pragma unroll
    for (int jp = 0; jp < 2; ++jp)
#pragma unroll
      for (int kk = 0; kk < 2; ++kk) bF[jp][kk] = rdB(Bt, jp, kk);
    __builtin_amdgcn_s_setprio(1);
#pragma unroll
    for (int ip = 0; ip < 4; ++ip)
#pragma unroll
      for (int jp = 0; jp < 2; ++jp)
#pragma unroll
        for (int kk = 0; kk < 2; ++kk)
          acc[ip][jp] = MFMA(aF[ip][kk], bF[jp][kk], acc[ip][jp], 0, 0, 0);
    __builtin_amdgcn_s_setprio(0);

    // ---- phase 2: (ig 0-3, jg 2-3); needs B-jh1 (+A-h1 rides along) ----
    if (more) { asm volatile("s_waitcnt vmcnt(1)" ::: "memory"); }
    else      { asm volatile("s_waitcnt vmcnt(0)" ::: "memory"); }
    __builtin_amdgcn_s_barrier();
    asm volatile("" ::: "memory");
    if (more) stageB(t + 1, 0);
#pragma unroll
    for (int jp = 0; jp < 2; ++jp)
#pragma unroll
      for (int kk = 0; kk < 2; ++kk) bF[jp][kk] = rdB(Bt, 2 + jp, kk);
    __builtin_amdgcn_s_setprio(1);
#pragma unroll
    for (int ip = 0; ip < 4; ++ip)
#pragma unroll
      for (int jp = 0; jp < 2; ++jp)
#pragma unroll
        for (int kk = 0; kk < 2; ++kk)
          acc[ip][2 + jp] = MFMA(aF[ip][kk], bF[jp][kk], acc[ip][2 + jp], 0, 0, 0);
    __builtin_amdgcn_s_setprio(0);

    // ---- phase 3: (ig 4-6, jg 2-3); A-h1 landed per ph2 wait+barrier ----
    if (more) stageB(t + 1, 1);
#pragma unroll
    for (int ip = 0; ip < 3; ++ip)
#pragma unroll
      for (int kk = 0; kk < 2; ++kk) aF[ip][kk] = rdA(At, 4 + ip, kk);
    __builtin_amdgcn_s_setprio(1);
#pragma unroll
    for (int ip = 0; ip < 3; ++ip)
#pragma unroll
      for (int jp = 0; jp < 2; ++jp)
#pragma unroll
        for (int kk = 0; kk < 2; ++kk)
          acc[4 + ip][2 + jp] = MFMA(aF[ip][kk], bF[jp][kk], acc[4 + ip][2 + jp], 0, 0, 0);
    __builtin_amdgcn_s_setprio(0);

    // ---- phase 4: (ig 4-6, jg 0-1); B-jh0 re-read ----
    if (more) stageA(t + 1, 1);
#pragma unroll
    for (int jp = 0; jp < 2; ++jp)
#pragma unroll
      for (int kk = 0; kk < 2; ++kk) bF[jp][kk] = rdB(Bt, jp, kk);
    __builtin_amdgcn_s_setprio(1);
#pragma unroll
    for (int ip = 0; ip < 3; ++ip)
#pragma unroll
      for (int jp = 0; jp < 2; ++jp)
#pragma unroll
        for (int kk = 0; kk < 2; ++kk)
          acc[4 + ip][jp] = MFMA(aF[ip][kk], bF[jp][kk], acc[4 + ip][jp], 0, 0, 0);
    __builtin_amdgcn_s_setprio(0);
  }

  // epilogue
  const float* bs = (EPI == 3 && head) ? bias2 : bias;
  float* of = (EPI == 3 && head) ? outf2 : outf;
#pragma unroll
  for (int jg = 0; jg < 4; ++jg) {
    int col = wid * 64 + jg * 16 + (lane & 15);
    float bb = bs[col];
#pragma unroll
    for (int ig = 0; ig < 7; ++ig) {
      int rbase = row0 + ig * 16 + (lane >> 4) * 4;
      f32x4 v = acc[ig][jg];
#pragma unroll
      for (int r = 0; r < 4; ++r) {
        int row = rbase + r;
        if (row < N_NODES) {
          float f = v[r] + bb;
          if (EPI == 0) {
            f = fmaxf(f, 0.f);
            outb[(size_t)row * DIM + col] = f2bf(f);
          } else if (EPI == 1) {
            outf[(size_t)row * DIM + col] = f;
            outb[(size_t)row * DIM + col] = f2bf(f);
          } else {
            of[(size_t)row * DIM + col] = fmaxf(f, 0.f);
          }
        }
      }
    }
  }
}

// ---------------- launch ----------------
extern "C" void kernel_launch(void* const* d_in, const int* in_sizes, int n_in,
                              void* d_out, int out_size, void* d_ws, size_t ws_size,
                              hipStream_t stream) {
  (void)in_sizes; (void)n_in; (void)out_size; (void)ws_size;
  const float* x   = (const float*)d_in[0];
  const int*   ei  = (const int*)d_in[1];
  const float* Wl0 = (const float*)d_in[2];
  const float* bl0 = (const float*)d_in[3];
  const float* Wr0 = (const float*)d_in[4];
  const float* Wl1 = (const float*)d_in[5];
  const float* bl1 = (const float*)d_in[6];
  const float* Wr1 = (const float*)d_in[7];
  const float* Wv  = (const float*)d_in[8];
  const float* bv  = (const float*)d_in[9];
  const float* Wt  = (const float*)d_in[10];
  const float* bt  = (const float*)d_in[11];
  const int* srcI = ei;
  const int* dstI = ei + N_EDGES;

  float* out_h = (float*)d_out;
  float* out_v = out_h + (size_t)N_NODES * DIM;
  float* out_t = out_v + (size_t)N_NODES * DIM;
  u16* meanb  = (u16*)out_v;  // scratch: bf16 mean buffer (consumed before final write)
  u16* hrelub = (u16*)out_t;  // scratch: bf16 relu(h0) buffer

  uint8_t* p = (uint8_t*)d_ws;
  auto carve = [&](size_t bytes) -> uint8_t* {
    uint8_t* r = p; p += (bytes + 1023) & ~(size_t)1023; return r;
  };
  int*   deg  = (int*)carve((size_t)N_NODES * 4);
  int*   offs = (int*)carve((size_t)(N_NODES + 1) * 4);
  int*   pos  = (int*)carve((size_t)N_NODES * 4);
  float* invd = (float*)carve((size_t)N_NODES * 4);
  int*   srcs = (int*)carve((size_t)N_EDGES * 4);
  u16* Wl0b = (u16*)carve(512 * 512 * 2);
  u16* Wr0b = (u16*)carve(512 * 512 * 2);
  u16* Wl1b = (u16*)carve(512 * 512 * 2);
  u16* Wr1b = (u16*)carve(512 * 512 * 2);
  u16* Wvb  = (u16*)carve(512 * 512 * 2);
  u16* Wtb  = (u16*)carve(512 * 512 * 2);
  u16* xb   = (u16*)carve((size_t)N_NODES * DIM * 2);  // x bf16, later h bf16

  const int EB = (N_EDGES + 255) / 256;

  k_zero<<<49, 256, 0, stream>>>((int4*)deg);
  k_prep<<<12500, 256, 0, stream>>>(x, xb, dstI, deg,
                                    Wl0, Wr0, Wl1, Wr1, Wv, Wt,
                                    Wl0b, Wr0b, Wl1b, Wr1b, Wvb, Wtb);
  k_scan<<<1, 1024, 0, stream>>>(deg, offs, pos, invd);
  k_scatter<<<EB, 256, 0, stream>>>(srcI, dstI, pos, srcs);

  const int GB = 448;  // 448 row tiles of 112 rows (448*112 = 50176)

  // layer 0: mean-agg(xb) -> meanb ; h0 = relu(mean@Wl0 + x@Wr0 + bl0) -> hrelub
  k_agg_bf16<<<12500, 256, 0, stream>>>(xb, offs, srcs, invd, meanb);
  k_gemm112<0><<<GB, 512, 0, stream>>>(meanb, Wl0b, xb, Wr0b, bl0, nullptr,
                                       nullptr, nullptr, hrelub, 16);

  // layer 1: mean-agg(hrelub) -> meanb ; h = mean@Wl1 + h0@Wr1 + bl1 -> out_h + xb
  k_agg_bf16<<<12500, 256, 0, stream>>>(hrelub, offs, srcs, invd, meanb);
  k_gemm112<1><<<GB, 512, 0, stream>>>(meanb, Wl1b, hrelub, Wr1b, bl1, nullptr,
                                       out_h, nullptr, xb, 16);

  // fused heads: relu(h@Wv + bv) -> out_v ; relu(h@Wt + bt) -> out_t
  k_gemm112<3><<<896, 512, 0, stream>>>(xb, Wvb, nullptr, Wtb, bv, bt,
                                        out_v, out_t, nullptr, 8);
}

// Round 8
// 642.411 us; speedup vs baseline: 1.2880x; 1.0066x over previous
//
#include <hip/hip_runtime.h>
#include <hip/hip_bf16.h>
#include <stdint.h>

#define N_NODES 50000
#define N_EDGES 500000
#define DIM 512

typedef unsigned short u16;
typedef unsigned int u32;
typedef __bf16 bf16x8 __attribute__((ext_vector_type(8)));
typedef float f32x4 __attribute__((ext_vector_type(4)));

static __device__ __forceinline__ u16 f2bf(float f) {
  union { __bf16 b; u16 u; } cv; cv.b = (__bf16)f; return cv.u;
}
static __device__ __forceinline__ float bf2f(u16 u) {
  union { u16 u; __bf16 b; } cv; cv.u = u; return (float)cv.b;
}

// ---------------- deg zero (rocclr blit path avoided) ----------------
__global__ void k_zero(int4* __restrict__ deg4) {
  int t = blockIdx.x * 256 + threadIdx.x;
  if (t < 12500) deg4[t] = make_int4(0, 0, 0, 0);  // 12500*16B = 200000B exact
}

// ---------------- CSR build ----------------
__global__ __launch_bounds__(1024) void k_scan(const int* __restrict__ deg,
                                               int* __restrict__ offs,
                                               int* __restrict__ pos,
                                               float* __restrict__ invd) {
  __shared__ int sums[1024];
  const int tid = threadIdx.x;
  const int CH = 49;  // 1024*49 = 50176 >= 50000
  int lo = tid * CH;
  int hi = lo + CH; if (hi > N_NODES) hi = N_NODES;
  if (lo > N_NODES) lo = N_NODES;
  int s = 0;
  for (int i = lo; i < hi; ++i) s += deg[i];
  sums[tid] = s;
  __syncthreads();
  for (int off = 1; off < 1024; off <<= 1) {
    int t = (tid >= off) ? sums[tid - off] : 0;
    __syncthreads();
    sums[tid] += t;
    __syncthreads();
  }
  int run = sums[tid] - s;  // exclusive prefix of this chunk
  for (int i = lo; i < hi; ++i) {
    int d = deg[i];
    offs[i] = run; pos[i] = run;
    invd[i] = 1.0f / (float)((d > 1) ? d : 1);
    run += d;
  }
  if (tid == 1023) offs[N_NODES] = run;
}

// srcs stores src*DIM (u16-element offset) so gather skips the multiply
__global__ void k_scatter(const int* __restrict__ src, const int* __restrict__ dst,
                          int* __restrict__ pos, int* __restrict__ srcs) {
  int e = blockIdx.x * blockDim.x + threadIdx.x;
  if (e < N_EDGES) {
    int p = atomicAdd(&pos[dst[e]], 1);
    srcs[p] = src[e] * DIM;
  }
}

// ---------------- fused prep: cvt_x + edge histogram + 6x weight transpose ----
__global__ __launch_bounds__(256) void k_prep(
    const float* __restrict__ x, u16* __restrict__ xb,
    const int* __restrict__ dst, int* __restrict__ deg,
    const float* __restrict__ Wa, const float* __restrict__ Wb,
    const float* __restrict__ Wc, const float* __restrict__ Wd,
    const float* __restrict__ We, const float* __restrict__ Wf,
    u16* __restrict__ Oa, u16* __restrict__ Ob, u16* __restrict__ Oc,
    u16* __restrict__ Od, u16* __restrict__ Oe, u16* __restrict__ Of) {
  __shared__ u16 tbuf[64][66];
  const int t = blockIdx.x * 256 + threadIdx.x;

  // --- cvt_x: 8 floats -> 8 bf16 per thread ---
  const float4* p = (const float4*)(x + (size_t)t * 8);
  float4 a = p[0], b = p[1];
  uint4 o;
  o.x = (u32)f2bf(a.x) | ((u32)f2bf(a.y) << 16);
  o.y = (u32)f2bf(a.z) | ((u32)f2bf(a.w) << 16);
  o.z = (u32)f2bf(b.x) | ((u32)f2bf(b.y) << 16);
  o.w = (u32)f2bf(b.z) | ((u32)f2bf(b.w) << 16);
  *(uint4*)(xb + (size_t)t * 8) = o;

  // --- edge degree histogram ---
  if (t < N_EDGES) atomicAdd(&deg[dst[t]], 1);

  // --- weight transpose (last 384 blocks) ---
  const int wb = (int)blockIdx.x - (12500 - 384);
  if (wb >= 0) {
    const float* W; u16* O;
    switch (wb / 64) {
      case 0: W = Wa; O = Oa; break;
      case 1: W = Wb; O = Ob; break;
      case 2: W = Wc; O = Oc; break;
      case 3: W = Wd; O = Od; break;
      case 4: W = We; O = Oe; break;
      default: W = Wf; O = Of; break;
    }
    const int rem = wb & 63;
    const int k0 = (rem & 7) * 64, n0 = (rem >> 3) * 64;
    const int lr = threadIdx.x & 63, wr = threadIdx.x >> 6;
#pragma unroll
    for (int rr = 0; rr < 16; ++rr) {
      int k = k0 + wr * 16 + rr;
      tbuf[lr][wr * 16 + rr] = f2bf(W[(size_t)k * 512 + n0 + lr]);
    }
    __syncthreads();
#pragma unroll
    for (int rr = 0; rr < 16; ++rr) {
      int n = n0 + wr * 16 + rr;
      O[(size_t)n * 512 + k0 + lr] = tbuf[wr * 16 + rr][lr];
    }
  }
}

// ---------------- aggregation: D-split half-pass gather ----------------------
// Probe (pre-committed): half = blockIdx>=12500 selects cols [half*256, +255].
// Hot gather slice per half-pass = 25.5 MB (vs 51 MB full) — tests whether the
// 5.3 TB/s agg floor is L3-miss-driven (H2: split helps) or request-rate
// (H1: null).  Per-column add order and two-bank alternation identical to the
// r7 baseline -> bit-identical output.
#define ACC2(A, q)                                              \
  A[0] += bf2f((q).x & 0xffff); A[1] += bf2f((u16)((q).x >> 16)); \
  A[2] += bf2f((q).y & 0xffff); A[3] += bf2f((u16)((q).y >> 16));

__global__ __launch_bounds__(256) void k_agg_half(
    const u16* __restrict__ hb, const int* __restrict__ offs,
    const int* __restrict__ srcs, const float* __restrict__ invd,
    u16* __restrict__ outb) {
  int bid = (int)blockIdx.x;
  const int half = (bid >= 12500) ? 1 : 0;
  if (half) bid -= 12500;
  const int node = bid * 4 + (threadIdx.x >> 6);   // 12500*4 = 50000 exact
  const int lane = threadIdx.x & 63;
  const int s0 = offs[node], s1 = offs[node + 1];
  float acc[4] = {0, 0, 0, 0};
  float acd[4] = {0, 0, 0, 0};
  const u16* hl = hb + half * 256 + lane * 4;      // 8B granule per lane
  int i = s0;
  for (; i + 8 <= s1; i += 8) {
    int sa = srcs[i], sb = srcs[i + 1], sc = srcs[i + 2], sd = srcs[i + 3];
    int se = srcs[i + 4], sf = srcs[i + 5], sg = srcs[i + 6], sh = srcs[i + 7];
    uint2 qa = *(const uint2*)(hl + sa);
    uint2 qb = *(const uint2*)(hl + sb);
    uint2 qc = *(const uint2*)(hl + sc);
    uint2 qd = *(const uint2*)(hl + sd);
    uint2 qe = *(const uint2*)(hl + se);
    uint2 qf = *(const uint2*)(hl + sf);
    uint2 qg = *(const uint2*)(hl + sg);
    uint2 qh = *(const uint2*)(hl + sh);
    ACC2(acc, qa) ACC2(acd, qb) ACC2(acc, qc) ACC2(acd, qd)
    ACC2(acc, qe) ACC2(acd, qf) ACC2(acc, qg) ACC2(acd, qh)
  }
  if (i + 4 <= s1) {
    int sa = srcs[i], sb = srcs[i + 1], sc = srcs[i + 2], sd = srcs[i + 3];
    uint2 qa = *(const uint2*)(hl + sa);
    uint2 qb = *(const uint2*)(hl + sb);
    uint2 qc = *(const uint2*)(hl + sc);
    uint2 qd = *(const uint2*)(hl + sd);
    ACC2(acc, qa) ACC2(acd, qb) ACC2(acc, qc) ACC2(acd, qd)
    i += 4;
  }
  if (i + 2 <= s1) {
    int sa = srcs[i], sb = srcs[i + 1];
    uint2 qa = *(const uint2*)(hl + sa);
    uint2 qb = *(const uint2*)(hl + sb);
    ACC2(acc, qa) ACC2(acd, qb)
    i += 2;
  }
  if (i < s1) {
    int sa = srcs[i];
    uint2 qa = *(const uint2*)(hl + sa);
    ACC2(acc, qa)
  }
  const float iv = invd[node];
#pragma unroll
  for (int k = 0; k < 4; ++k) acc[k] = (acc[k] + acd[k]) * iv;
  uint2 o;
  o.x = (u32)f2bf(acc[0]) | ((u32)f2bf(acc[1]) << 16);
  o.y = (u32)f2bf(acc[2]) | ((u32)f2bf(acc[3]) << 16);
  *(uint2*)(outb + (size_t)node * DIM + half * 256 + lane * 4) = o;
}

// ---------------- GEMM: 112x512 tile, BK=64, 8 waves, 4-phase pipeline --------
// Best-measured structure (r4/r7, 646.7 us pipeline): counted vmcnt (T4),
// XOR-chunk LDS swizzle (T2), setprio (T5), 4-phase interleave (T3-lite).
// r6 proved a 2-phase vmcnt(0) replacement costs +82 us (m233 stall class).
#define MFMA __builtin_amdgcn_mfma_f32_16x16x32_bf16
#define BUFU 39936  // u16 per buffer: A 7168 + B 32768

template <int EPI>
__global__ __launch_bounds__(512, 2) void k_gemm112(
    const u16* __restrict__ A1, const u16* __restrict__ W1,
    const u16* __restrict__ A2, const u16* __restrict__ W2,
    const float* __restrict__ bias, const float* __restrict__ bias2,
    float* __restrict__ outf, float* __restrict__ outf2,
    u16* __restrict__ outb, int NT) {
  __shared__ u16 lds[2 * BUFU];  // 156 KB
  const int tid = threadIdx.x;
  const int wid = tid >> 6, lane = tid & 63;
  int head = 0, row0;
  if (EPI == 3) {
    head = (int)blockIdx.x & 1;
    row0 = ((int)blockIdx.x >> 1) * 112;
  } else {
    row0 = (int)blockIdx.x * 112;
  }
  const u16* BW = (EPI == 3) ? (head ? W2 : W1) : nullptr;

  f32x4 acc[7][4];
  const f32x4 z = {0.f, 0.f, 0.f, 0.f};
#pragma unroll
  for (int i = 0; i < 7; ++i)
#pragma unroll
    for (int j = 0; j < 4; ++j) acc[i][j] = z;

  const int ly = lane >> 3;
  const int schunk = (lane & 7) ^ ly;

  auto stageA = [&](int t, int h) {
    u16* tile = lds + (t & 1) * BUFU;
    const u16* G = (EPI == 3) ? A1 : ((t < 8) ? A1 : A2);
    int w = wid;
    if (h && w >= 6) w -= 2;  // duplicate rows 96..111 (same src+dest, benign)
    const int rb = h * 64 + w * 8;
    int rg = row0 + rb + ly;
    if (rg > N_NODES - 1) rg = N_NODES - 1;
    const u16* g = G + (size_t)rg * 512 + (t & 7) * 64 + schunk * 8;
    __builtin_amdgcn_global_load_lds(
        (const __attribute__((address_space(1))) void*)g,
        (__attribute__((address_space(3))) void*)(tile + rb * 64), 16, 0, 0);
  };

  auto stageB = [&](int t, int jh) {
    u16* tile = lds + (t & 1) * BUFU + 7168;
    const u16* G = (EPI == 3) ? BW : ((t < 8) ? W1 : W2);
    const int kofs = (t & 7) * 64 + schunk * 8;
#pragma unroll
    for (int u = 0; u < 4; ++u) {
      const int rb = u * 128 + (wid >> 2) * 64 + (wid & 3) * 8 + jh * 32;
      const u16* g = G + (size_t)(rb + ly) * 512 + kofs;
      __builtin_amdgcn_global_load_lds(
          (const __attribute__((address_space(1))) void*)g,
          (__attribute__((address_space(3))) void*)(tile + rb * 64), 16, 0, 0);
    }
  };

  auto rdA = [&](const u16* T_, int ig, int kk) -> bf16x8 {
    const int r = ig * 16 + (lane & 15);
    const int off = ((kk * 4 + (lane >> 4)) ^ (lane & 7)) * 8;
    return *(const bf16x8*)(T_ + r * 64 + off);
  };
  auto rdB = [&](const u16* T_, int jg, int kk) -> bf16x8 {
    const int r = wid * 64 + jg * 16 + (lane & 15);
    const int off = ((kk * 4 + (lane >> 4)) ^ (lane & 7)) * 8;
    return *(const bf16x8*)(T_ + r * 64 + off);
  };

  stageA(0, 0); stageB(0, 0); stageB(0, 1); stageA(0, 1);

  for (int t = 0; t < NT; ++t) {
    const u16* At = lds + (t & 1) * BUFU;
    const u16* Bt = At + 7168;
    const bool more = (t + 1 < NT);
    bf16x8 aF[4][2], bF[2][2];

    // ---- phase 1: (ig 0-3, jg 0-1); needs A-h0 + B-jh0 ----
    asm volatile("s_waitcnt vmcnt(5)" ::: "memory");
    __builtin_amdgcn_s_barrier();
    asm volatile("" ::: "memory");
    if (more) stageA(t + 1, 0);
#pragma unroll
    for (int ip = 0; ip < 4; ++ip)
#pragma unroll
      for (int kk = 0; kk < 2; ++kk) aF[ip][kk] = rdA(At, ip, kk);
#pragma unroll
    for (int jp = 0; jp < 2; ++jp)
#pragma unroll
      for (int kk = 0; kk < 2; ++kk) bF[jp][kk] = rdB(Bt, jp, kk);
    __builtin_amdgcn_s_setprio(1);
#pragma unroll
    for (int ip = 0; ip < 4; ++ip)
#pragma unroll
      for (int jp = 0; jp < 2; ++jp)
#pragma unroll
        for (int kk = 0; kk < 2; ++kk)
          acc[ip][jp] = MFMA(aF[ip][kk], bF[jp][kk], acc[ip][jp], 0, 0, 0);
    __builtin_amdgcn_s_setprio(0);

    // ---- phase 2: (ig 0-3, jg 2-3); needs B-jh1 (+A-h1 rides along) ----
    if (more) { asm volatile("s_waitcnt vmcnt(1)" ::: "memory"); }
    else      { asm volatile("s_waitcnt vmcnt(0)" ::: "memory"); }
    __builtin_amdgcn_s_barrier();
    asm volatile("" ::: "memory");
    if (more) stageB(t + 1, 0);
#pragma unroll
    for (int jp = 0; jp < 2; ++jp)
#pragma unroll
      for (int kk = 0; kk < 2; ++kk) bF[jp][kk] = rdB(Bt, 2 + jp, kk);
    __builtin_amdgcn_s_setprio(1);
#pragma unroll
    for (int ip = 0; ip < 4; ++ip)
#pragma unroll
      for (int jp = 0; jp < 2; ++jp)
#pragma unroll
        for (int kk = 0; kk < 2; ++kk)
          acc[ip][2 + jp] = MFMA(aF[ip][kk], bF[jp][kk], acc[ip][2 + jp], 0, 0, 0);
    __builtin_amdgcn_s_setprio(0);

    // ---- phase 3: (ig 4-6, jg 2-3); A-h1 landed per ph2 wait+barrier ----
    if (more) stageB(t + 1, 1);
#pragma unroll
    for (int ip = 0; ip < 3; ++ip)
#pragma unroll
      for (int kk = 0; kk < 2; ++kk) aF[ip][kk] = rdA(At, 4 + ip, kk);
    __builtin_amdgcn_s_setprio(1);
#pragma unroll
    for (int ip = 0; ip < 3; ++ip)
#pragma unroll
      for (int jp = 0; jp < 2; ++jp)
#pragma unroll
        for (int kk = 0; kk < 2; ++kk)
          acc[4 + ip][2 + jp] = MFMA(aF[ip][kk], bF[jp][kk], acc[4 + ip][2 + jp], 0, 0, 0);
    __builtin_amdgcn_s_setprio(0);

    // ---- phase 4: (ig 4-6, jg 0-1); B-jh0 re-read ----
    if (more) stageA(t + 1, 1);
#pragma unroll
    for (int jp = 0; jp < 2; ++jp)
#pragma unroll
      for (int kk = 0; kk < 2; ++kk) bF[jp][kk] = rdB(Bt, jp, kk);
    __builtin_amdgcn_s_setprio(1);
#pragma unroll
    for (int ip = 0; ip < 3; ++ip)
#pragma unroll
      for (int jp = 0; jp < 2; ++jp)
#pragma unroll
        for (int kk = 0; kk < 2; ++kk)
          acc[4 + ip][jp] = MFMA(aF[ip][kk], bF[jp][kk], acc[4 + ip][jp], 0, 0, 0);
    __builtin_amdgcn_s_setprio(0);
  }

  // epilogue
  const float* bs = (EPI == 3 && head) ? bias2 : bias;
  float* of = (EPI == 3 && head) ? outf2 : outf;
#pragma unroll
  for (int jg = 0; jg < 4; ++jg) {
    int col = wid * 64 + jg * 16 + (lane & 15);
    float bb = bs[col];
#pragma unroll
    for (int ig = 0; ig < 7; ++ig) {
      int rbase = row0 + ig * 16 + (lane >> 4) * 4;
      f32x4 v = acc[ig][jg];
#pragma unroll
      for (int r = 0; r < 4; ++r) {
        int row = rbase + r;
        if (row < N_NODES) {
          float f = v[r] + bb;
          if (EPI == 0) {
            f = fmaxf(f, 0.f);
            outb[(size_t)row * DIM + col] = f2bf(f);
          } else if (EPI == 1) {
            outf[(size_t)row * DIM + col] = f;
            outb[(size_t)row * DIM + col] = f2bf(f);
          } else {
            of[(size_t)row * DIM + col] = fmaxf(f, 0.f);
          }
        }
      }
    }
  }
}

// ---------------- launch ----------------
extern "C" void kernel_launch(void* const* d_in, const int* in_sizes, int n_in,
                              void* d_out, int out_size, void* d_ws, size_t ws_size,
                              hipStream_t stream) {
  (void)in_sizes; (void)n_in; (void)out_size; (void)ws_size;
  const float* x   = (const float*)d_in[0];
  const int*   ei  = (const int*)d_in[1];
  const float* Wl0 = (const float*)d_in[2];
  const float* bl0 = (const float*)d_in[3];
  const float* Wr0 = (const float*)d_in[4];
  const float* Wl1 = (const float*)d_in[5];
  const float* bl1 = (const float*)d_in[6];
  const float* Wr1 = (const float*)d_in[7];
  const float* Wv  = (const float*)d_in[8];
  const float* bv  = (const float*)d_in[9];
  const float* Wt  = (const float*)d_in[10];
  const float* bt  = (const float*)d_in[11];
  const int* srcI = ei;
  const int* dstI = ei + N_EDGES;

  float* out_h = (float*)d_out;
  float* out_v = out_h + (size_t)N_NODES * DIM;
  float* out_t = out_v + (size_t)N_NODES * DIM;
  u16* meanb  = (u16*)out_v;  // scratch: bf16 mean buffer (consumed before final write)
  u16* hrelub = (u16*)out_t;  // scratch: bf16 relu(h0) buffer

  uint8_t* p = (uint8_t*)d_ws;
  auto carve = [&](size_t bytes) -> uint8_t* {
    uint8_t* r = p; p += (bytes + 1023) & ~(size_t)1023; return r;
  };
  int*   deg  = (int*)carve((size_t)N_NODES * 4);
  int*   offs = (int*)carve((size_t)(N_NODES + 1) * 4);
  int*   pos  = (int*)carve((size_t)N_NODES * 4);
  float* invd = (float*)carve((size_t)N_NODES * 4);
  int*   srcs = (int*)carve((size_t)N_EDGES * 4);
  u16* Wl0b = (u16*)carve(512 * 512 * 2);
  u16* Wr0b = (u16*)carve(512 * 512 * 2);
  u16* Wl1b = (u16*)carve(512 * 512 * 2);
  u16* Wr1b = (u16*)carve(512 * 512 * 2);
  u16* Wvb  = (u16*)carve(512 * 512 * 2);
  u16* Wtb  = (u16*)carve(512 * 512 * 2);
  u16* xb   = (u16*)carve((size_t)N_NODES * DIM * 2);  // x bf16, later h bf16

  const int EB = (N_EDGES + 255) / 256;

  k_zero<<<49, 256, 0, stream>>>((int4*)deg);
  k_prep<<<12500, 256, 0, stream>>>(x, xb, dstI, deg,
                                    Wl0, Wr0, Wl1, Wr1, Wv, Wt,
                                    Wl0b, Wr0b, Wl1b, Wr1b, Wvb, Wtb);
  k_scan<<<1, 1024, 0, stream>>>(deg, offs, pos, invd);
  k_scatter<<<EB, 256, 0, stream>>>(srcI, dstI, pos, srcs);

  const int GB = 448;  // 448 row tiles of 112 rows (448*112 = 50176)

  // layer 0: D-split mean-agg(xb) -> meanb ; h0 = relu(mean@Wl0 + x@Wr0 + bl0)
  k_agg_half<<<25000, 256, 0, stream>>>(xb, offs, srcs, invd, meanb);
  k_gemm112<0><<<GB, 512, 0, stream>>>(meanb, Wl0b, xb, Wr0b, bl0, nullptr,
                                       nullptr, nullptr, hrelub, 16);

  // layer 1: D-split mean-agg(hrelub) -> meanb ; h -> out_h f32 + xb bf16
  k_agg_half<<<25000, 256, 0, stream>>>(hrelub, offs, srcs, invd, meanb);
  k_gemm112<1><<<GB, 512, 0, stream>>>(meanb, Wl1b, hrelub, Wr1b, bl1, nullptr,
                                       out_h, nullptr, xb, 16);

  // fused heads: relu(h@Wv + bv) -> out_v ; relu(h@Wt + bt) -> out_t
  k_gemm112<3><<<896, 512, 0, stream>>>(xb, Wvb, nullptr, Wtb, bv, bt,
                                        out_v, out_t, nullptr, 8);
}